// Round 4
// baseline (740.438 us; speedup 1.0000x reference)
//
#include <hip/hip_runtime.h>

#define SEQ 1024
#define BN  512
#define NT  64

__global__ void zero_out_kernel(float* o) { o[0] = 0.0f; }

// wave-uniform broadcast of lane i of v (compiler keeps result in an SGPR)
#define RL(v, i) __int_as_float(__builtin_amdgcn_readlane(__float_as_int(v), (i)))

// repeat a macro for 0..63 (used for E register decl/init)
#define RPT64(M) \
  M(0)  M(1)  M(2)  M(3)  M(4)  M(5)  M(6)  M(7)  \
  M(8)  M(9)  M(10) M(11) M(12) M(13) M(14) M(15) \
  M(16) M(17) M(18) M(19) M(20) M(21) M(22) M(23) \
  M(24) M(25) M(26) M(27) M(28) M(29) M(30) M(31) \
  M(32) M(33) M(34) M(35) M(36) M(37) M(38) M(39) \
  M(40) M(41) M(42) M(43) M(44) M(45) M(46) M(47) \
  M(48) M(49) M(50) M(51) M(52) M(53) M(54) M(55) \
  M(56) M(57) M(58) M(59) M(60) M(61) M(62) M(63)

// E[i][lane] = exp(trans[i][lane]) as 64 NAMED scalars -> cannot be demoted
// to scratch (no arrays, no dynamic indexing). ~64 VGPRs.
#define EDECL(i) float E##i = __expf(trans[(i) * NT + lane]);

// four rotating accumulator chains; u_i broadcast via readlane -> SGPR,
// consumed as the scalar operand of v_fmac_f32
#define FMAQ(i0, i1, i2, i3)                  \
  a0 = fmaf(RL(u, i0), E##i0, a0);            \
  a1 = fmaf(RL(u, i1), E##i1, a1);            \
  a2 = fmaf(RL(u, i2), E##i2, a2);            \
  a3 = fmaf(RL(u, i3), E##i3, a3);

extern "C" __global__ __launch_bounds__(64, 1)
void crf_kernel(const float* __restrict__ emis,
                const int*   __restrict__ tags,
                const int*   __restrict__ mask,
                const float* __restrict__ startT,
                const float* __restrict__ endT,
                const float* __restrict__ trans,
                float* __restrict__ out)
{
    const int b    = blockIdx.x;
    const int lane = threadIdx.x;

    // small LDS: numerator transition table + this batch's tag/mask columns.
    // Per-step DS is just 3 b32 reads — matvec uses NO LDS at all.
    __shared__ __align__(16) float strans[NT * NT];
    __shared__ int stag[SEQ];
    __shared__ int smk[SEQ];

    // ---- one-time staging (single wave, in-order DS, no barriers) ----
    {
        const float4* t4 = (const float4*)trans;
        float4* s4 = (float4*)strans;
        #pragma unroll
        for (int k = 0; k < 16; ++k)
            s4[k * NT + lane] = t4[k * NT + lane];
    }
    #pragma unroll
    for (int c = 0; c < SEQ / NT; ++c) {
        int t = c * NT + lane;
        stag[t] = tags[t * BN + b];
        smk[t]  = mask[t * BN + b];
    }
    __threadfence_block();

    // ---- E in registers ----
    RPT64(EDECL)

    // ---- t = 0 init ----
    float em0    = emis[(0 * BN + b) * NT + lane];
    int   tg_p   = stag[0];
    float alpha0 = startT[lane] + em0;
    float M = __int_as_float(__builtin_amdgcn_readfirstlane(__float_as_int(alpha0)));
    float u = __expf(alpha0 - M);            // u_0 == 1
    float score = (lane == tg_p) ? alpha0 : 0.0f;
    int   lt    = tg_p;
    int   esum  = 0;

    // ---- depth-4 emissions prefetch (the ONLY vmem in the loop) ----
    float emA = emis[(1 * BN + b) * NT + lane];
    float emB = emis[(2 * BN + b) * NT + lane];
    float emC = emis[(3 * BN + b) * NT + lane];
    float emD = emis[(4 * BN + b) * NT + lane];

    for (int t = 1; t < SEQ; ++t) {
        const float em_t = emA;
        emA = emB; emB = emC; emC = emD;
        int tn = t + 4; if (tn > SEQ - 1) tn = SEQ - 1;
        emD = emis[(tn * BN + b) * NT + lane];

        const int   tg_t = stag[t];                  // LDS broadcast b32
        const int   mk_t = smk[t];
        const float Trow = strans[tg_p * NT + lane]; // conflict-free b32

        float w = __expf(em_t);                      // off the u-chain

        // s_j = sum_i u_i * E[i][j]; readlane->SGPR x FMA, zero memory traffic
        float a0 = 0.f, a1 = 0.f, a2 = 0.f, a3 = 0.f;
        FMAQ( 0,  1,  2,  3)  FMAQ( 4,  5,  6,  7)
        FMAQ( 8,  9, 10, 11)  FMAQ(12, 13, 14, 15)
        FMAQ(16, 17, 18, 19)  FMAQ(20, 21, 22, 23)
        FMAQ(24, 25, 26, 27)  FMAQ(28, 29, 30, 31)
        FMAQ(32, 33, 34, 35)  FMAQ(36, 37, 38, 39)
        FMAQ(40, 41, 42, 43)  FMAQ(44, 45, 46, 47)
        FMAQ(48, 49, 50, 51)  FMAQ(52, 53, 54, 55)
        FMAQ(56, 57, 58, 59)  FMAQ(60, 61, 62, 63)
        float s   = (a0 + a1) + (a2 + a3);
        float swv = s * w;

        // exponent-only renorm: shift by lane-0's biased exponent (exact int
        // accumulation replaces per-step logf)
        int ex = (__float_as_int(swv) >> 23) & 255;
        int e  = __builtin_amdgcn_readfirstlane(ex);
        float un = ldexpf(swv, 127 - e);

        if (mk_t) {                                   // wave-uniform
            u = un;
            esum += e - 127;
            if (lane == tg_t) score += em_t + Trow;
            lt = tg_t;
        }
        tg_p = tg_t;
    }

    // ---- epilogue ----
    if (lane == lt) score += endT[lane];
    float v  = u * __expf(endT[lane]);
    float sp = score;
    #pragma unroll
    for (int off = 32; off > 0; off >>= 1) {
        v  += __shfl_xor(v,  off, 64);
        sp += __shfl_xor(sp, off, 64);
    }
    if (lane == 0) {
        float denom = M + (float)esum * 0.69314718055994531f + __logf(v);
        atomicAdd(out, sp - denom);
    }
}

extern "C" void kernel_launch(void* const* d_in, const int* in_sizes, int n_in,
                              void* d_out, int out_size, void* d_ws, size_t ws_size,
                              hipStream_t stream)
{
    const float* emis   = (const float*)d_in[0];
    const int*   tags   = (const int*)  d_in[1];
    const int*   mask   = (const int*)  d_in[2];
    const float* startT = (const float*)d_in[3];
    const float* endT   = (const float*)d_in[4];
    const float* trans  = (const float*)d_in[5];
    float* out = (float*)d_out;

    zero_out_kernel<<<1, 1, 0, stream>>>(out);
    crf_kernel<<<dim3(BN), dim3(NT), 0, stream>>>(emis, tags, mask,
                                                  startT, endT, trans, out);
}

// Round 5
// 470.442 us; speedup vs baseline: 1.5739x; 1.5739x over previous
//
#include <hip/hip_runtime.h>

#define SEQ 1024
#define BN  512
#define NT  64

typedef float f2 __attribute__((ext_vector_type(2)));

__global__ void zero_out_kernel(float* o) { o[0] = 0.0f; }

#define RPT16(M) M(0) M(1) M(2) M(3) M(4) M(5) M(6) M(7) \
                 M(8) M(9) M(10) M(11) M(12) M(13) M(14) M(15)

// E rows 4k..4k+3 for this lane, as two NAMED float2 (static access only ->
// stays in VGPRs; round-4 demotion came from dynamic vector indexing)
#define ED(k)                                                          \
  f2 E##k##_0 = { __expf(trans[(4*(k)+0) * NT + lane]),                \
                  __expf(trans[(4*(k)+1) * NT + lane]) };              \
  f2 E##k##_1 = { __expf(trans[(4*(k)+2) * NT + lane]),                \
                  __expf(trans[(4*(k)+3) * NT + lane]) };

// one su float4 chunk -> two v_pk_fma_f32 into chains A,B
#define CH(k, A, B) {                                                  \
    float4 v = su4[k];                                                 \
    f2 lo = { v.x, v.y };                                              \
    f2 hi = { v.z, v.w };                                              \
    A = __builtin_elementwise_fma(lo, E##k##_0, A);                    \
    B = __builtin_elementwise_fma(hi, E##k##_1, B);                    \
  }

extern "C" __global__ __launch_bounds__(64, 1)
void crf_kernel(const float* __restrict__ emis,
                const int*   __restrict__ tags,
                const int*   __restrict__ mask,
                const float* __restrict__ startT,
                const float* __restrict__ endT,
                const float* __restrict__ trans,
                float* __restrict__ out)
{
    const int b    = blockIdx.x;
    const int lane = threadIdx.x;

    // LDS: numerator transition table + packed (tag|mask<<16) + u vector.
    // Per-step DS: 16 b128 su broadcasts + 1 write + 2 b32 reads.
    __shared__ __align__(16) float strans[NT * NT];
    __shared__ __align__(16) float su[NT];
    __shared__ int spk[SEQ];

    // ---- one-time staging (single wave, in-order DS, no barriers) ----
    {
        const float4* t4 = (const float4*)trans;
        float4* s4 = (float4*)strans;
        #pragma unroll
        for (int k = 0; k < 16; ++k)
            s4[k * NT + lane] = t4[k * NT + lane];
    }
    #pragma unroll
    for (int c = 0; c < SEQ / NT; ++c) {
        int t = c * NT + lane;
        spk[t] = (tags[t * BN + b] & 0xFFFF) | (mask[t * BN + b] << 16);
    }
    __threadfence_block();

    // ---- E in registers: 32 named float2 (64 VGPRs) ----
    RPT16(ED)

    // ---- t = 0 init ----
    float em0    = emis[(0 * BN + b) * NT + lane];
    int   tg_p   = spk[0] & 0xFFFF;
    float alpha0 = startT[lane] + em0;
    float M = __int_as_float(__builtin_amdgcn_readfirstlane(__float_as_int(alpha0)));
    float u = __expf(alpha0 - M);            // u_0 == 1
    float score = (lane == tg_p) ? alpha0 : 0.0f;
    int   lt    = tg_p;
    int   esum  = 0;
    su[lane] = u;

    // ---- depth-4 emissions prefetch (the ONLY vmem in the loop) ----
    float emA = emis[(1 * BN + b) * NT + lane];
    float emB = emis[(2 * BN + b) * NT + lane];
    float emC = emis[(3 * BN + b) * NT + lane];
    float emD = emis[(4 * BN + b) * NT + lane];

    #pragma unroll 2
    for (int t = 1; t < SEQ; ++t) {
        const float em_t = emA;
        emA = emB; emB = emC; emC = emD;
        int tn = t + 4; if (tn > SEQ - 1) tn = SEQ - 1;
        emD = emis[(tn * BN + b) * NT + lane];

        const int   pk   = spk[t];                   // tag | mask<<16
        const int   tg_t = pk & 0xFFFF;
        const int   mk_t = pk >> 16;
        const float Trow = strans[tg_p * NT + lane]; // conflict-free b32

        float w = __expf(em_t);                      // off the u-chain

        // s_j = sum_i u_i * E[i][j]: su b128 broadcasts x E-in-regs,
        // 8 packed-FMA chains (32 v_pk_fma_f32), depth 4
        const float4* su4 = (const float4*)su;
        f2 A0 = {0.f, 0.f}, A1 = {0.f, 0.f}, A2 = {0.f, 0.f}, A3 = {0.f, 0.f};
        f2 B0 = {0.f, 0.f}, B1 = {0.f, 0.f}, B2 = {0.f, 0.f}, B3 = {0.f, 0.f};
        CH( 0, A0, B0) CH( 1, A1, B1) CH( 2, A2, B2) CH( 3, A3, B3)
        CH( 4, A0, B0) CH( 5, A1, B1) CH( 6, A2, B2) CH( 7, A3, B3)
        CH( 8, A0, B0) CH( 9, A1, B1) CH(10, A2, B2) CH(11, A3, B3)
        CH(12, A0, B0) CH(13, A1, B1) CH(14, A2, B2) CH(15, A3, B3)
        f2 S = ((A0 + A1) + (A2 + A3)) + ((B0 + B1) + (B2 + B3));
        float s   = S.x + S.y;
        float swv = s * w;

        // exponent-only renorm: shift by lane-0's biased exponent; exact
        // integer accumulation replaces per-step logf
        int ex = (__float_as_int(swv) >> 23) & 255;
        int e  = __builtin_amdgcn_readfirstlane(ex);
        float un = ldexpf(swv, 127 - e);

        if (mk_t) {                                   // wave-uniform
            u = un;
            esum += e - 127;
            if (lane == tg_t) score += em_t + Trow;
            lt = tg_t;
        }
        su[lane] = u;                                 // in-order DS pipe
        tg_p = tg_t;
    }

    // ---- epilogue ----
    if (lane == lt) score += endT[lane];
    float v  = u * __expf(endT[lane]);
    float sp = score;
    #pragma unroll
    for (int off = 32; off > 0; off >>= 1) {
        v  += __shfl_xor(v,  off, 64);
        sp += __shfl_xor(sp, off, 64);
    }
    if (lane == 0) {
        float denom = M + (float)esum * 0.69314718055994531f + __logf(v);
        atomicAdd(out, sp - denom);
    }
}

extern "C" void kernel_launch(void* const* d_in, const int* in_sizes, int n_in,
                              void* d_out, int out_size, void* d_ws, size_t ws_size,
                              hipStream_t stream)
{
    const float* emis   = (const float*)d_in[0];
    const int*   tags   = (const int*)  d_in[1];
    const int*   mask   = (const int*)  d_in[2];
    const float* startT = (const float*)d_in[3];
    const float* endT   = (const float*)d_in[4];
    const float* trans  = (const float*)d_in[5];
    float* out = (float*)d_out;

    zero_out_kernel<<<1, 1, 0, stream>>>(out);
    crf_kernel<<<dim3(BN), dim3(NT), 0, stream>>>(emis, tags, mask,
                                                  startT, endT, trans, out);
}